// Round 5
// baseline (183.679 us; speedup 1.0000x reference)
//
#include <hip/hip_runtime.h>

typedef unsigned short ushort_t;
typedef unsigned int uint_t;

#define BKT_SHIFT 7            // 128 dst-nodes per bucket
#define BKT_NODES 128
#define NBKT_MAX 800           // >= ceil(100000/128)=782
#define BCAP 4096              // slots/bucket; mean 3200, sigma~57 -> +15.8 sigma
#define EPB 8192               // edges per scatter block (512 thr x 16 in regs)

__device__ __forceinline__ ushort_t f2bf(float f) {
    unsigned u = __float_as_uint(f);
    unsigned r = (u + 0x7FFFu + ((u >> 16) & 1u)) >> 16;   // RNE
    return (ushort_t)r;
}
__device__ __forceinline__ float bflo(uint_t u) { return __uint_as_float(u << 16); }
__device__ __forceinline__ float bfhi(uint_t u) { return __uint_as_float(u & 0xFFFF0000u); }

// ---- fat kernel: bucket-grouped scatter  ||  z1 = x @ W1 (bf16) --------
// Scatter blocks: 16 edges/thread in regs; LDS histogram; ONE global
// atomicAdd per (block,bucket) claims a contiguous range (validated ~306
// claims/address); block-local scan + LDS place groups the block's edges by
// bucket; WAVE-PER-BUCKET write-out makes the global stores coalesced runs
// (fixes the measured 9x write amplification of per-edge scattered stores).
// Lin blocks: per-node 32->16 matvec, bf16 out (GIN distributivity:
// (x_i + sum x_j)@W1 = z_i + sum z_j -> aggregate in 16-ch z-space;
// z table = 3.2 MB -> per-XCD-L2-resident, gather order irrelevant).
__global__ __launch_bounds__(512) void scatter_lin(
    const int* __restrict__ src, const int* __restrict__ dst,
    int* __restrict__ gcnt, int* __restrict__ staged,
    const float4* __restrict__ x4, const float* __restrict__ W,
    ushort_t* __restrict__ z, int E, int SBLK, int N, int NBKT)
{
    __shared__ float sW[512];
    __shared__ int lcnt[NBKT_MAX];
    __shared__ int lbase[NBKT_MAX];
    __shared__ int lcur[NBKT_MAX];
    __shared__ int bpre[NBKT_MAX];
    __shared__ int swsum[512];
    __shared__ int sstage[EPB];        // 32 KB: block's edges grouped by bucket
    int t = threadIdx.x, blk = blockIdx.x;
    if (blk < SBLK) {
        for (int b = t; b < NBKT; b += 512) { lcnt[b] = 0; lcur[b] = 0; }
        __syncthreads();
        int e0 = blk * EPB;
        int rd[16], rs[16];
        #pragma unroll
        for (int i = 0; i < 16; ++i) {
            int e = e0 + i * 512 + t;
            bool ok = (e < E);
            rd[i] = ok ? dst[e] : -1;
            rs[i] = ok ? src[e] : 0;
            if (ok) atomicAdd(&lcnt[rd[i] >> BKT_SHIFT], 1);
        }
        __syncthreads();
        for (int b = t; b < NBKT; b += 512)
            lbase[b] = atomicAdd(&gcnt[b], lcnt[b]);
        // block-local exclusive bucket prefix (2 buckets/thread + 512-scan)
        int j0 = t * 2;
        int c0 = (j0     < NBKT) ? lcnt[j0]     : 0;
        int c1 = (j0 + 1 < NBKT) ? lcnt[j0 + 1] : 0;
        swsum[t] = c0 + c1;
        __syncthreads();
        for (int off = 1; off < 512; off <<= 1) {
            int add = (t >= off) ? swsum[t - off] : 0;
            __syncthreads();
            swsum[t] += add;
            __syncthreads();
        }
        int excl = swsum[t] - (c0 + c1);
        if (j0     < NBKT) bpre[j0]     = excl;
        if (j0 + 1 < NBKT) bpre[j0 + 1] = excl + c0;
        __syncthreads();
        // place into LDS grouped by bucket (per-edge atomics stay in LDS)
        #pragma unroll
        for (int i = 0; i < 16; ++i) {
            if (rd[i] >= 0) {
                int b = rd[i] >> BKT_SHIFT;
                int r = atomicAdd(&lcur[b], 1);
                sstage[bpre[b] + r] = ((rd[i] & (BKT_NODES - 1)) << 24) | rs[i];
            }
        }
        __syncthreads();
        // wave-per-bucket coalesced flush: consecutive lanes -> consecutive slots
        int wid = t >> 6, lane = t & 63;
        for (int b = wid; b < NBKT; b += 8) {
            int cnt = lcnt[b];
            int gb  = lbase[b];
            int lb  = bpre[b];
            for (int k = lane; k < cnt; k += 64) {
                int gs = gb + k;
                if (gs < BCAP)   // statistically unreachable overflow guard
                    staged[(size_t)b * BCAP + gs] = sstage[lb + k];
            }
        }
    } else {
        sW[t] = W[t];                      // 32x16 = 512 floats
        __syncthreads();
        int n = (blk - SBLK) * 512 + t;
        if (n >= N) return;
        float a[16];
        #pragma unroll
        for (int c = 0; c < 16; ++c) a[c] = 0.f;
        const float4* xr = x4 + (size_t)n * 8;
        #pragma unroll
        for (int k4 = 0; k4 < 8; ++k4) {
            float4 xv = xr[k4];
            #pragma unroll
            for (int c = 0; c < 16; ++c) {
                a[c] += xv.x * sW[(k4 * 4 + 0) * 16 + c];
                a[c] += xv.y * sW[(k4 * 4 + 1) * 16 + c];
                a[c] += xv.z * sW[(k4 * 4 + 2) * 16 + c];
                a[c] += xv.w * sW[(k4 * 4 + 3) * 16 + c];
            }
        }
        uint_t w[8];
        #pragma unroll
        for (int i2 = 0; i2 < 8; ++i2)
            w[i2] = (uint_t)f2bf(a[2 * i2]) | ((uint_t)f2bf(a[2 * i2 + 1]) << 16);
        uint4* zo = (uint4*)(z + (size_t)n * 16);
        uint4 q0; q0.x = w[0]; q0.y = w[1]; q0.z = w[2]; q0.w = w[3];
        uint4 q1; q1.x = w[4]; q1.y = w[5]; q1.z = w[6]; q1.w = w[7];
        zo[0] = q0;     // cacheable: consumed by agg gathers next
        zo[1] = q1;
    }
}

// ---- shared gather + pair-shuffle MLP core -----------------------------
// 2 lanes per node (sl=0/1), uint4 = 8 bf16 channels per lane: halves the
// gather instruction count vs 4-lane/uint2 at the same cacheline traffic.
// Cross-lane MLP via __shfl_xor(.,1) within the node pair -> no sh/sr LDS.

__device__ __forceinline__ void gather_acc(
    const uint4* __restrict__ zp, const int* __restrict__ scol,
    int k, int ke, int sl, float* acc)
{
    for (; k + 8 <= ke; k += 8) {
        uint4 uu[8];
        #pragma unroll
        for (int j = 0; j < 8; ++j)
            uu[j] = zp[(size_t)scol[k + j] * 2 + sl];
        #pragma unroll
        for (int j = 0; j < 8; ++j) {
            acc[0] += bflo(uu[j].x); acc[1] += bfhi(uu[j].x);
            acc[2] += bflo(uu[j].y); acc[3] += bfhi(uu[j].y);
            acc[4] += bflo(uu[j].z); acc[5] += bfhi(uu[j].z);
            acc[6] += bflo(uu[j].w); acc[7] += bfhi(uu[j].w);
        }
    }
    for (; k < ke; ++k) {
        uint4 u = zp[(size_t)scol[k] * 2 + sl];
        acc[0] += bflo(u.x); acc[1] += bfhi(u.x);
        acc[2] += bflo(u.y); acc[3] += bfhi(u.y);
        acc[4] += bflo(u.z); acc[5] += bfhi(u.z);
        acc[6] += bflo(u.w); acc[7] += bfhi(u.w);
    }
}

// h = ReLU(acc + ba); o[16] = h @ Wb(16x32) + bb for out-ch 16*sl..16*sl+15
__device__ __forceinline__ void mlp_front(
    const float* acc, const float* sba, const float* sWb, const float* sbb,
    int sl, float* o)
{
    float h[8], hp[8];
    #pragma unroll
    for (int j = 0; j < 8; ++j) h[j] = fmaxf(acc[j] + sba[sl * 8 + j], 0.f);
    #pragma unroll
    for (int j = 0; j < 8; ++j) hp[j] = __shfl_xor(h[j], 1);
    float hl[8], hh[8];
    #pragma unroll
    for (int j = 0; j < 8; ++j) {
        hl[j] = sl ? hp[j] : h[j];     // h channels 0..7
        hh[j] = sl ? h[j] : hp[j];     // h channels 8..15
    }
    int ocb = sl * 16;
    #pragma unroll
    for (int i = 0; i < 16; ++i) o[i] = sbb[ocb + i];
    #pragma unroll
    for (int j = 0; j < 8; ++j) {
        #pragma unroll
        for (int i = 0; i < 16; ++i) {
            o[i] += hl[j] * sWb[j * 32 + ocb + i];
            o[i] += hh[j] * sWb[(j + 8) * 32 + ocb + i];
        }
    }
}

// ---- agg1: sort staged -> scol (spill) + conv1 MLP -> z2 ---------------
__global__ __launch_bounds__(256) void agg1(
    const ushort_t* __restrict__ zin, const int* __restrict__ staged,
    const int* __restrict__ gcnt,
    int* __restrict__ colg, int2* __restrict__ rp2,
    const float* __restrict__ ba,
    const float* __restrict__ Wb, const float* __restrict__ bb,
    const float* __restrict__ Wc,
    ushort_t* __restrict__ z2, int N)
{
    __shared__ float sWb[512];     // 16x32
    __shared__ float sWc[512];     // 32x16
    __shared__ float sba[16], sbb[32];
    __shared__ int scnt[512], srel[512], scur[512];   // [node][src&3]
    __shared__ int sns[128];
    __shared__ int snode[129];
    __shared__ int scol[BCAP];     // 16 KB

    int t = threadIdx.x;
    sWb[t] = Wb[t];  sWb[t + 256] = Wb[t + 256];
    sWc[t] = Wc[t];  sWc[t + 256] = Wc[t + 256];
    if (t < 16) sba[t] = ba[t];
    if (t < 32) sbb[t] = bb[t];
    scnt[t] = 0; scnt[t + 256] = 0;
    scur[t] = 0; scur[t + 256] = 0;
    __syncthreads();

    int b = blockIdx.x;
    int m = min(gcnt[b], BCAP);
    const int* sp = staged + (size_t)b * BCAP;

    // count by (node, s&3) -- subkey spreads the LDS atomics
    for (int i = t; i < m; i += 256) {
        int v = sp[i];
        atomicAdd(&scnt[(((unsigned)v >> 24) << 2) | (v & 3)], 1);
    }
    __syncthreads();
    int c0 = 0, c1 = 0, c2 = 0, c3 = 0, tot = 0;
    if (t < 128) {
        c0 = scnt[t * 4 + 0]; c1 = scnt[t * 4 + 1];
        c2 = scnt[t * 4 + 2]; c3 = scnt[t * 4 + 3];
        tot = c0 + c1 + c2 + c3;
        sns[t] = tot;
    }
    __syncthreads();
    for (int off = 1; off < 128; off <<= 1) {   // Hillis over 128 node totals
        int add = (t < 128 && t >= off) ? sns[t - off] : 0;
        __syncthreads();
        if (t < 128) sns[t] += add;
        __syncthreads();
    }
    if (t < 128) {
        int excl = sns[t] - tot;
        srel[t * 4 + 0] = excl;
        srel[t * 4 + 1] = excl + c0;
        srel[t * 4 + 2] = excl + c0 + c1;
        srel[t * 4 + 3] = excl + c0 + c1 + c2;
        snode[t] = excl;
        if (t == 127) snode[128] = sns[127];
    }
    __syncthreads();
    // ranked place (staged run L2-hot from count pass)
    for (int i = t; i < m; i += 256) {
        int v = sp[i];
        int idx = (((unsigned)v >> 24) << 2) | (v & 3);
        int p = srel[idx] + atomicAdd(&scur[idx], 1);
        scol[p] = v & 0xFFFFFF;
    }
    __syncthreads();
    // spill sorted CSR for agg2 (coalesced)
    for (int i = t; i < m; i += 256)
        colg[(size_t)b * BCAP + i] = scol[i];
    int base = b << BKT_SHIFT;
    if (t < 128 && base + t < N)
        rp2[base + t] = make_int2(b * BCAP + snode[t], b * BCAP + snode[t + 1]);

    // gather + conv1 MLP
    int ln = t >> 1, sl = t & 1;
    int n = base + ln;
    if (n < N) {
        const uint4* zp = (const uint4*)zin;
        uint4 us = zp[(size_t)n * 2 + sl];     // self term
        float acc[8] = { bflo(us.x), bfhi(us.x), bflo(us.y), bfhi(us.y),
                         bflo(us.z), bfhi(us.z), bflo(us.w), bfhi(us.w) };
        gather_acc(zp, scol, snode[ln], snode[ln + 1], sl, acc);
        float o[16];
        mlp_front(acc, sba, sWb, sbb, sl, o);
        // z_next[16] = ReLU(o32) @ Wc(32x16); lane has 16 of 32 rows
        float p[16];
        #pragma unroll
        for (int zc = 0; zc < 16; ++zc) p[zc] = 0.f;
        int ocb = sl * 16;
        #pragma unroll
        for (int i = 0; i < 16; ++i) {
            float r = fmaxf(o[i], 0.f);
            #pragma unroll
            for (int zc = 0; zc < 16; ++zc)
                p[zc] += r * sWc[(ocb + i) * 16 + zc];
        }
        float pm[8], po[8];
        #pragma unroll
        for (int k = 0; k < 8; ++k) {
            pm[k] = sl ? p[8 + k] : p[k];      // partial for my z-ch block
            po[k] = sl ? p[k] : p[8 + k];      // partial for partner's block
        }
        #pragma unroll
        for (int k = 0; k < 8; ++k) po[k] = __shfl_xor(po[k], 1);
        uint_t w[4];
        #pragma unroll
        for (int k = 0; k < 4; ++k) {
            float zA = pm[2 * k]     + po[2 * k];
            float zB = pm[2 * k + 1] + po[2 * k + 1];
            w[k] = (uint_t)f2bf(zA) | ((uint_t)f2bf(zB) << 16);
        }
        uint4 q; q.x = w[0]; q.y = w[1]; q.z = w[2]; q.w = w[3];
        ((uint4*)z2)[(size_t)n * 2 + sl] = q;  // cacheable: conv2 gathers it
    }
}

// ---- agg2: pure gather + conv2 MLP (reads spilled CSR, no sort) --------
__global__ __launch_bounds__(256) void agg2(
    const ushort_t* __restrict__ zin, const int* __restrict__ colg,
    const int2* __restrict__ rp2,
    const float* __restrict__ ba,
    const float* __restrict__ Wb, const float* __restrict__ bb,
    float* __restrict__ out, int N)
{
    __shared__ float sWb[512];
    __shared__ float sba[16], sbb[32];
    __shared__ int scol[BCAP];

    int t = threadIdx.x;
    sWb[t] = Wb[t];  sWb[t + 256] = Wb[t + 256];
    if (t < 16) sba[t] = ba[t];
    if (t < 32) sbb[t] = bb[t];

    int b = blockIdx.x;
    int base = b << BKT_SHIFT;
    int kb = b * BCAP;
    int last = min(base + BKT_NODES, N) - 1;
    int m = rp2[last].y - kb;
    for (int i = t; i < m; i += 256)
        scol[i] = __builtin_nontemporal_load(colg + (size_t)kb + i);
    __syncthreads();

    int ln = t >> 1, sl = t & 1;
    int n = base + ln;
    if (n < N) {
        const uint4* zp = (const uint4*)zin;
        uint4 us = zp[(size_t)n * 2 + sl];
        float acc[8] = { bflo(us.x), bfhi(us.x), bflo(us.y), bfhi(us.y),
                         bflo(us.z), bfhi(us.z), bflo(us.w), bfhi(us.w) };
        int2 r = rp2[n];
        gather_acc(zp, scol, r.x - kb, r.y - kb, sl, acc);
        float o[16];
        mlp_front(acc, sba, sWb, sbb, sl, o);
        float* op = out + (size_t)n * 32 + sl * 16;
        #pragma unroll
        for (int i = 0; i < 16; ++i)
            __builtin_nontemporal_store(o[i], op + i);
    }
}

// ---- Launch -------------------------------------------------------------

extern "C" void kernel_launch(void* const* d_in, const int* in_sizes, int n_in,
                              void* d_out, int out_size, void* d_ws, size_t ws_size,
                              hipStream_t stream) {
    const float* x  = (const float*)d_in[0];
    const int*   ei = (const int*)d_in[1];
    const float* W1 = (const float*)d_in[2];
    const float* b1 = (const float*)d_in[3];
    const float* W2 = (const float*)d_in[4];
    const float* b2 = (const float*)d_in[5];
    const float* W3 = (const float*)d_in[6];
    const float* b3 = (const float*)d_in[7];
    const float* W4 = (const float*)d_in[8];
    const float* b4 = (const float*)d_in[9];

    const int N = in_sizes[0] / 32;
    const int E = in_sizes[1] / 2;
    const int* src = ei;
    const int* dst = ei + E;

    const int NBKT = (N + BKT_NODES - 1) >> BKT_SHIFT;   // 782
    const int SBLK = (E + EPB - 1) / EPB;                // 306
    const int LINB = (N + 511) / 512;                    // 196

    char* ws = (char*)d_ws;
    size_t o = 0;
    auto alloc = [&](size_t bytes) -> char* {
        o = (o + 255) & ~(size_t)255;
        char* r = ws + o;
        o += bytes;
        return r;
    };
    int*      gcnt   = (int*)     alloc(4 * (size_t)NBKT);
    int*      staged = (int*)     alloc(4 * (size_t)NBKT * BCAP);   // 12.8 MB
    int*      colg   = (int*)     alloc(4 * (size_t)NBKT * BCAP);   // 12.8 MB
    int2*     rp2    = (int2*)    alloc(8 * (size_t)N);
    ushort_t* zb     = (ushort_t*)alloc(2 * (size_t)N * 16);        // z1 = x@W1
    ushort_t* z2b    = (ushort_t*)alloc(2 * (size_t)N * 16);        // z2 = relu(out1)@W3

    hipMemsetAsync(gcnt, 0, 4 * (size_t)NBKT, stream);

    scatter_lin<<<SBLK + LINB, 512, 0, stream>>>(
        src, dst, gcnt, staged, (const float4*)x, W1, zb, E, SBLK, N, NBKT);

    agg1<<<NBKT, 256, 0, stream>>>(
        zb, staged, gcnt, colg, rp2, b1, W2, b2, W3, z2b, N);
    agg2<<<NBKT, 256, 0, stream>>>(
        z2b, colg, rp2, b3, W4, b4, (float*)d_out, N);
}

// Round 7
// 180.002 us; speedup vs baseline: 1.0204x; 1.0204x over previous
//
#include <hip/hip_runtime.h>

typedef unsigned short ushort_t;
typedef unsigned int uint_t;

#define BKT_SHIFT 7            // 128 dst-nodes per bucket
#define BKT_NODES 128
#define NBKT_MAX 800           // >= ceil(100000/128)=782
#define BCAP 4096              // slots/bucket; mean 3200, sigma~57 -> +15.8 sigma
#define EPB 8192               // edges per scatter block (512 thr x 16 in regs)

__device__ __forceinline__ ushort_t f2bf(float f) {
    unsigned u = __float_as_uint(f);
    unsigned r = (u + 0x7FFFu + ((u >> 16) & 1u)) >> 16;   // RNE
    return (ushort_t)r;
}
__device__ __forceinline__ float bflo(uint_t u) { return __uint_as_float(u << 16); }
__device__ __forceinline__ float bfhi(uint_t u) { return __uint_as_float(u & 0xFFFF0000u); }

// ---- fat kernel: range-claim bucket scatter  ||  z1 = x @ W1 (bf16) ----
// (round-4 scatter logic verbatim, re-parameterized to 782 buckets.)
// Scatter blocks: 16 edges/thread in REGISTERS; LDS histogram; ONE global
// atomicAdd per (block,bucket) claims a contiguous range (~306 claims per
// address -> parallel across addresses); place via LDS rank atomics.
// Per-edge atomics never leave LDS (round-2 lesson).
// Lin blocks: per-node 32->16 matvec, bf16 out (GIN distributivity:
// (x_i + sum x_j)@W1 = z_i + sum z_j -> aggregate in 16-ch z-space;
// z table = 3.2 MB -> per-XCD-L2-resident, gather order irrelevant).
__global__ __launch_bounds__(512) void scatter_lin(
    const int* __restrict__ src, const int* __restrict__ dst,
    int* __restrict__ gcnt, int* __restrict__ staged,
    const float4* __restrict__ x4, const float* __restrict__ W,
    ushort_t* __restrict__ z, int E, int SBLK, int N, int NBKT)
{
    __shared__ float sW[512];
    __shared__ int lcnt[NBKT_MAX];
    __shared__ int lbase[NBKT_MAX];
    __shared__ int lcur[NBKT_MAX];
    int t = threadIdx.x, blk = blockIdx.x;
    if (blk < SBLK) {
        for (int b = t; b < NBKT; b += 512) { lcnt[b] = 0; lcur[b] = 0; }
        __syncthreads();
        int e0 = blk * EPB;
        int rd[16], rs[16];
        #pragma unroll
        for (int i = 0; i < 16; ++i) {
            int e = e0 + i * 512 + t;
            bool ok = (e < E);
            rd[i] = ok ? dst[e] : -1;
            rs[i] = ok ? src[e] : 0;
            if (ok) atomicAdd(&lcnt[rd[i] >> BKT_SHIFT], 1);
        }
        __syncthreads();
        for (int b = t; b < NBKT; b += 512)
            lbase[b] = atomicAdd(&gcnt[b], lcnt[b]);
        __syncthreads();
        #pragma unroll
        for (int i = 0; i < 16; ++i) {
            if (rd[i] >= 0) {
                int b = rd[i] >> BKT_SHIFT;
                int r = lbase[b] + atomicAdd(&lcur[b], 1);
                if (r < BCAP)   // statistically unreachable overflow guard
                    staged[(size_t)b * BCAP + r] =
                        ((rd[i] & (BKT_NODES - 1)) << 24) | rs[i];
            }
        }
    } else {
        sW[t] = W[t];                      // 32x16 = 512 floats
        __syncthreads();
        int n = (blk - SBLK) * 512 + t;
        if (n >= N) return;
        float a[16];
        #pragma unroll
        for (int c = 0; c < 16; ++c) a[c] = 0.f;
        const float4* xr = x4 + (size_t)n * 8;
        #pragma unroll
        for (int k4 = 0; k4 < 8; ++k4) {
            float4 xv = xr[k4];
            #pragma unroll
            for (int c = 0; c < 16; ++c) {
                a[c] += xv.x * sW[(k4 * 4 + 0) * 16 + c];
                a[c] += xv.y * sW[(k4 * 4 + 1) * 16 + c];
                a[c] += xv.z * sW[(k4 * 4 + 2) * 16 + c];
                a[c] += xv.w * sW[(k4 * 4 + 3) * 16 + c];
            }
        }
        uint_t w[8];
        #pragma unroll
        for (int i2 = 0; i2 < 8; ++i2)
            w[i2] = (uint_t)f2bf(a[2 * i2]) | ((uint_t)f2bf(a[2 * i2 + 1]) << 16);
        uint4* zo = (uint4*)(z + (size_t)n * 16);
        uint4 q0; q0.x = w[0]; q0.y = w[1]; q0.z = w[2]; q0.w = w[3];
        uint4 q1; q1.x = w[4]; q1.y = w[5]; q1.z = w[6]; q1.w = w[7];
        zo[0] = q0;     // cacheable: consumed by agg gathers next
        zo[1] = q1;
    }
}

// ---- shared gather + pair-shuffle MLP core (verified in round 5) -------
// 2 lanes per node (sl=0/1), uint4 = 8 bf16 channels per lane: HALF the
// gather VMEM instructions vs 4-lane/uint2 at identical cacheline traffic.
// Cross-lane MLP via __shfl_xor(.,1) within the node pair -> no sh/sr LDS.

__device__ __forceinline__ void gather_acc(
    const uint4* __restrict__ zp, const int* __restrict__ scol,
    int k, int ke, int sl, float* acc)
{
    for (; k + 8 <= ke; k += 8) {
        uint4 uu[8];
        #pragma unroll
        for (int j = 0; j < 8; ++j)
            uu[j] = zp[(size_t)scol[k + j] * 2 + sl];
        #pragma unroll
        for (int j = 0; j < 8; ++j) {
            acc[0] += bflo(uu[j].x); acc[1] += bfhi(uu[j].x);
            acc[2] += bflo(uu[j].y); acc[3] += bfhi(uu[j].y);
            acc[4] += bflo(uu[j].z); acc[5] += bfhi(uu[j].z);
            acc[6] += bflo(uu[j].w); acc[7] += bfhi(uu[j].w);
        }
    }
    for (; k < ke; ++k) {
        uint4 u = zp[(size_t)scol[k] * 2 + sl];
        acc[0] += bflo(u.x); acc[1] += bfhi(u.x);
        acc[2] += bflo(u.y); acc[3] += bfhi(u.y);
        acc[4] += bflo(u.z); acc[5] += bfhi(u.z);
        acc[6] += bflo(u.w); acc[7] += bfhi(u.w);
    }
}

// h = ReLU(acc + ba); o[16] = h @ Wb(16x32) + bb for out-ch 16*sl..16*sl+15
__device__ __forceinline__ void mlp_front(
    const float* acc, const float* sba, const float* sWb, const float* sbb,
    int sl, float* o)
{
    float h[8], hp[8];
    #pragma unroll
    for (int j = 0; j < 8; ++j) h[j] = fmaxf(acc[j] + sba[sl * 8 + j], 0.f);
    #pragma unroll
    for (int j = 0; j < 8; ++j) hp[j] = __shfl_xor(h[j], 1);
    float hl[8], hh[8];
    #pragma unroll
    for (int j = 0; j < 8; ++j) {
        hl[j] = sl ? hp[j] : h[j];     // h channels 0..7
        hh[j] = sl ? h[j] : hp[j];     // h channels 8..15
    }
    int ocb = sl * 16;
    #pragma unroll
    for (int i = 0; i < 16; ++i) o[i] = sbb[ocb + i];
    #pragma unroll
    for (int j = 0; j < 8; ++j) {
        #pragma unroll
        for (int i = 0; i < 16; ++i) {
            o[i] += hl[j] * sWb[j * 32 + ocb + i];
            o[i] += hh[j] * sWb[(j + 8) * 32 + ocb + i];
        }
    }
}

// ---- Fused sort + aggregate + MLP (round-4 structure, new core) --------
// One 256-thread block per 128-node bucket (782 blocks, ~3/CU). Phase 1:
// sort the bucket's staged run into LDS scol (count by (node, s&3) ->
// 128-node Hillis scan -> ranked place; round-5-verified logic). Phase 2:
// 2-lane-per-node uint4 gather + pair-shuffle MLP.
//   CHAIN:  z_next = ReLU(o)@Wc -> bf16 (feeds conv2's aggregation)
//   !CHAIN: o -> fp32 final output

template <bool CHAIN>
__global__ __launch_bounds__(256) void agg_sort_mlp(
    const ushort_t* __restrict__ zin, const int* __restrict__ staged,
    const int* __restrict__ gcnt,
    const float* __restrict__ ba,
    const float* __restrict__ Wb, const float* __restrict__ bb,
    const float* __restrict__ Wc,
    void* __restrict__ outv, int N)
{
    __shared__ float sWb[512];     // 16x32
    __shared__ float sWc[512];     // 32x16 (CHAIN only)
    __shared__ float sba[16], sbb[32];
    __shared__ int scnt[512], srel[512], scur[512];   // [node][src&3]
    __shared__ int sns[128];
    __shared__ int snode[129];
    __shared__ int scol[BCAP];     // 16 KB

    int t = threadIdx.x;
    sWb[t] = Wb[t];  sWb[t + 256] = Wb[t + 256];
    if (CHAIN) { sWc[t] = Wc[t];  sWc[t + 256] = Wc[t + 256]; }
    if (t < 16) sba[t] = ba[t];
    if (t < 32) sbb[t] = bb[t];
    scnt[t] = 0; scnt[t + 256] = 0;
    scur[t] = 0; scur[t + 256] = 0;
    __syncthreads();

    int b = blockIdx.x;
    int m = min(gcnt[b], BCAP);
    const int* sp = staged + (size_t)b * BCAP;

    // count by (node, s&3) -- subkey spreads the LDS atomics
    for (int i = t; i < m; i += 256) {
        int v = sp[i];
        atomicAdd(&scnt[(((unsigned)v >> 24) << 2) | (v & 3)], 1);
    }
    __syncthreads();
    int c0 = 0, c1 = 0, c2 = 0, c3 = 0, tot = 0;
    if (t < 128) {
        c0 = scnt[t * 4 + 0]; c1 = scnt[t * 4 + 1];
        c2 = scnt[t * 4 + 2]; c3 = scnt[t * 4 + 3];
        tot = c0 + c1 + c2 + c3;
        sns[t] = tot;
    }
    __syncthreads();
    for (int off = 1; off < 128; off <<= 1) {   // Hillis over 128 node totals
        int add = (t < 128 && t >= off) ? sns[t - off] : 0;
        __syncthreads();
        if (t < 128) sns[t] += add;
        __syncthreads();
    }
    if (t < 128) {
        int excl = sns[t] - tot;
        srel[t * 4 + 0] = excl;
        srel[t * 4 + 1] = excl + c0;
        srel[t * 4 + 2] = excl + c0 + c1;
        srel[t * 4 + 3] = excl + c0 + c1 + c2;
        snode[t] = excl;
        if (t == 127) snode[128] = sns[127];
    }
    __syncthreads();
    // ranked place (staged run L2-hot from count pass)
    for (int i = t; i < m; i += 256) {
        int v = sp[i];
        int idx = (((unsigned)v >> 24) << 2) | (v & 3);
        int p = srel[idx] + atomicAdd(&scur[idx], 1);
        scol[p] = v & 0xFFFFFF;
    }
    __syncthreads();

    // gather + MLP
    int ln = t >> 1, sl = t & 1;
    int base = b << BKT_SHIFT;
    int n = base + ln;
    if (n < N) {
        const uint4* zp = (const uint4*)zin;
        uint4 us = zp[(size_t)n * 2 + sl];     // self term
        float acc[8] = { bflo(us.x), bfhi(us.x), bflo(us.y), bfhi(us.y),
                         bflo(us.z), bfhi(us.z), bflo(us.w), bfhi(us.w) };
        gather_acc(zp, scol, snode[ln], snode[ln + 1], sl, acc);
        float o[16];
        mlp_front(acc, sba, sWb, sbb, sl, o);
        if (CHAIN) {
            // z_next[16] = ReLU(o32) @ Wc(32x16); this lane has 16 of 32 rows
            float p[16];
            #pragma unroll
            for (int zc = 0; zc < 16; ++zc) p[zc] = 0.f;
            int ocb = sl * 16;
            #pragma unroll
            for (int i = 0; i < 16; ++i) {
                float r = fmaxf(o[i], 0.f);
                #pragma unroll
                for (int zc = 0; zc < 16; ++zc)
                    p[zc] += r * sWc[(ocb + i) * 16 + zc];
            }
            float pm[8], po[8];
            #pragma unroll
            for (int k = 0; k < 8; ++k) {
                pm[k] = sl ? p[8 + k] : p[k];      // partial for my z-ch block
                po[k] = sl ? p[k] : p[8 + k];      // partial for partner's
            }
            #pragma unroll
            for (int k = 0; k < 8; ++k) po[k] = __shfl_xor(po[k], 1);
            uint_t w[4];
            #pragma unroll
            for (int k = 0; k < 4; ++k) {
                float zA = pm[2 * k]     + po[2 * k];
                float zB = pm[2 * k + 1] + po[2 * k + 1];
                w[k] = (uint_t)f2bf(zA) | ((uint_t)f2bf(zB) << 16);
            }
            uint4 q; q.x = w[0]; q.y = w[1]; q.z = w[2]; q.w = w[3];
            ((uint4*)outv)[(size_t)n * 2 + sl] = q;  // cacheable: conv2 gathers
        } else {
            float* op = (float*)outv + (size_t)n * 32 + sl * 16;
            #pragma unroll
            for (int i = 0; i < 16; ++i)
                __builtin_nontemporal_store(o[i], op + i);
        }
    }
}

// ---- Launch -------------------------------------------------------------

extern "C" void kernel_launch(void* const* d_in, const int* in_sizes, int n_in,
                              void* d_out, int out_size, void* d_ws, size_t ws_size,
                              hipStream_t stream) {
    const float* x  = (const float*)d_in[0];
    const int*   ei = (const int*)d_in[1];
    const float* W1 = (const float*)d_in[2];
    const float* b1 = (const float*)d_in[3];
    const float* W2 = (const float*)d_in[4];
    const float* b2 = (const float*)d_in[5];
    const float* W3 = (const float*)d_in[6];
    const float* b3 = (const float*)d_in[7];
    const float* W4 = (const float*)d_in[8];
    const float* b4 = (const float*)d_in[9];

    const int N = in_sizes[0] / 32;
    const int E = in_sizes[1] / 2;
    const int* src = ei;
    const int* dst = ei + E;

    const int NBKT = (N + BKT_NODES - 1) >> BKT_SHIFT;   // 782
    const int SBLK = (E + EPB - 1) / EPB;                // 306
    const int LINB = (N + 511) / 512;                    // 196

    char* ws = (char*)d_ws;
    size_t o = 0;
    auto alloc = [&](size_t bytes) -> char* {
        o = (o + 255) & ~(size_t)255;
        char* r = ws + o;
        o += bytes;
        return r;
    };
    int*      gcnt   = (int*)     alloc(4 * (size_t)NBKT);
    int*      staged = (int*)     alloc(4 * (size_t)NBKT * BCAP);   // 12.8 MB
    ushort_t* zb     = (ushort_t*)alloc(2 * (size_t)N * 16);        // z1 = x@W1
    ushort_t* z2b    = (ushort_t*)alloc(2 * (size_t)N * 16);        // z2 = relu(out1)@W3

    hipMemsetAsync(gcnt, 0, 4 * (size_t)NBKT, stream);

    scatter_lin<<<SBLK + LINB, 512, 0, stream>>>(
        src, dst, gcnt, staged, (const float4*)x, W1, zb, E, SBLK, N, NBKT);

    agg_sort_mlp<true ><<<NBKT, 256, 0, stream>>>(
        zb, staged, gcnt, b1, W2, b2, W3, z2b, N);
    agg_sort_mlp<false><<<NBKT, 256, 0, stream>>>(
        z2b, staged, gcnt, b3, W4, b4, nullptr, (float*)d_out, N);
}